// Round 3
// baseline (618.465 us; speedup 1.0000x reference)
//
#include <hip/hip_runtime.h>

#define NB     64
#define CCH    256
#define HW     20480       // 128*160
#define NBATCH 4
#define NPIX   (NBATCH*HW) // 81920
#define NIDXBLK (NPIX/256) // 320
#define GRID_MS 512        // k_msum blocks (2048 waves)

// Workspace layout (bytes), total 303752 (R1-verified to fit ws_size)
#define WS_SUMS   0          // [2][64][256] f32 (131072), zeroed by k_idx
#define WS_HIST   131072     // [320][65] u16 (41600)
#define WS_IDX    172672     // [81920] u8, dead after k_msum main phase
#define WS_PS     172672     // aliases idx (safe: tail runs after all idx reads)
#define WS_PT     238208
#define WS_ACC    303744
#define WS_TICKET 303748

typedef __attribute__((ext_vector_type(8))) short short8;
typedef __attribute__((ext_vector_type(4))) float f32x4;

__device__ inline unsigned short f2bf(float f) {   // fp32 -> bf16 RNE
    unsigned u = __float_as_uint(f);
    return (unsigned short)((u + 0x7FFFu + ((u >> 16) & 1u)) >> 16);
}

// ---------------------------------------------------------------------------
// K1: bin index per pixel + per-block histogram; zero sums/ticket.
__global__ __launch_bounds__(256) void k_idx(const float* __restrict__ depth,
                                             unsigned char* __restrict__ idx,
                                             unsigned short* __restrict__ hist,
                                             float* __restrict__ sums,
                                             unsigned int* __restrict__ ticket) {
    __shared__ int h[NB + 1];
    int t = threadIdx.x, blk = blockIdx.x;
    if (t < NB + 1) h[t] = 0;
    __syncthreads();
    int p = blk * 256 + t;
    float f = depth[p] * 64.0f;
    int b;
    if (!(f >= 0.0f) || f > 64.0f) b = NB;   // NaN via !(f>=0)
    else b = (int)f;                         // f==64.0 -> 64 (matches ref)
    idx[p] = (unsigned char)b;
    atomicAdd(&h[b], 1);
    if (p < 2 * NB * CCH) sums[p] = 0.0f;
    if (p == 0) *ticket = 0u;
    __syncthreads();
    if (t < NB + 1) hist[blk * (NB + 1) + t] = (unsigned short)h[t];
}

// ---------------------------------------------------------------------------
// K2: segment-sum as one-hot MFMA + fused tail in last block.
// Wave task: (tensor, 64-channel slice, 320-pixel K-chunk).
// D[bin][ch] += onehot(A) * x_bf16hi(B) + onehot * x_bf16lo(B).
// 16x16x32 bf16 layouts (m89/m118/m120-verified):
//   A: m=lane&15, k=(lane>>4)*8+j   B: n=lane&15, k=(lane>>4)*8+j
//   D: col(n)=lane&15, row(m)=(lane>>4)*4+reg
__global__ __launch_bounds__(256) void k_msum(const float* __restrict__ predsS,
                                              const float* __restrict__ predsT,
                                              const unsigned char* __restrict__ idx,
                                              float* __restrict__ sums,
                                              const unsigned short* __restrict__ hist,
                                              float* __restrict__ pS,
                                              float* __restrict__ pT,
                                              unsigned int* __restrict__ ticket,
                                              float* __restrict__ out) {
    int tid = threadIdx.x;
    int lane = tid & 63;
    int wv = tid >> 6;
    int waveId = blockIdx.x * 4 + wv;         // 0..2047
    int tensor = waveId >> 10;
    int cslice = (waveId >> 8) & 3;
    int chunk  = waveId & 255;                // 256 chunks of 320 px
    int n   = chunk >> 6;
    int hw0 = (chunk & 63) * 320;
    int q   = lane >> 4;
    int l15 = lane & 15;
    int cbase = cslice * 64;

    const float* src = (tensor ? predsT : predsS)
                     + ((size_t)(n * CCH + cbase + l15) * HW + hw0 + q * 8);
    const unsigned char* ip = idx + n * HW + hw0 + q * 8;

    f32x4 acc[4][4];
    #pragma unroll
    for (int a = 0; a < 4; ++a)
        #pragma unroll
        for (int b = 0; b < 4; ++b) acc[a][b] = (f32x4)0.0f;

    #pragma unroll 2
    for (int step = 0; step < 10; ++step) {
        unsigned long long iv = *(const unsigned long long*)(ip + step * 32);
        short8 afr[4];
        #pragma unroll
        for (int mt = 0; mt < 4; ++mt) {
            int tgt = mt * 16 + l15;
            #pragma unroll
            for (int j = 0; j < 8; ++j) {
                int byte = (int)((iv >> (8 * j)) & 0xFFull);
                afr[mt][j] = (byte == tgt) ? (short)0x3F80 : (short)0;
            }
        }
        #pragma unroll
        for (int nt = 0; nt < 4; ++nt) {
            const float* p = src + (size_t)nt * 16 * HW + step * 32;
            float4 f0 = *(const float4*)p;
            float4 f1 = *(const float4*)(p + 4);
            float fv[8] = {f0.x, f0.y, f0.z, f0.w, f1.x, f1.y, f1.z, f1.w};
            short8 bhi, blo;
            #pragma unroll
            for (int j = 0; j < 8; ++j) {
                unsigned short h = f2bf(fv[j]);
                bhi[j] = (short)h;
                float hf = __uint_as_float(((unsigned)h) << 16);
                blo[j] = (short)f2bf(fv[j] - hf);
            }
            #pragma unroll
            for (int mt = 0; mt < 4; ++mt) {
                acc[mt][nt] = __builtin_amdgcn_mfma_f32_16x16x32_bf16(afr[mt], bhi, acc[mt][nt], 0, 0, 0);
                acc[mt][nt] = __builtin_amdgcn_mfma_f32_16x16x32_bf16(afr[mt], blo, acc[mt][nt], 0, 0, 0);
            }
        }
    }

    // Flush partial sums (global atomics; ~524k 64B line-RMWs total — cheap)
    float* dst = sums + (size_t)tensor * NB * CCH + cbase;
    #pragma unroll
    for (int mt = 0; mt < 4; ++mt)
        #pragma unroll
        for (int nt = 0; nt < 4; ++nt)
            #pragma unroll
            for (int r = 0; r < 4; ++r) {
                int bin = mt * 16 + q * 4 + r;
                int ch  = nt * 16 + l15;
                atomicAdd(&dst[bin * CCH + ch], acc[mt][nt][r]);
            }
    __threadfence();
    __syncthreads();
    __shared__ unsigned int rank_s;
    if (tid == 0) rank_s = atomicAdd(ticket, 1u);
    __syncthreads();
    if (rank_s != GRID_MS - 1) return;
    __threadfence();   // acquire: all other blocks' atomics now visible

    // ---------------- fused tail (single block) ----------------
    __shared__ float cntf[NB];
    __shared__ int   cnti[NB];
    __shared__ float redw[4];
    if (tid < NB) cnti[tid] = 0;
    __syncthreads();
    {   // counts: 256 threads = 64 bins x 4 chunks of 80 blocks
        int b = tid & 63, part = tid >> 6;
        int s = 0;
        for (int k = 0; k < 80; ++k)
            s += (int)hist[(part * 80 + k) * (NB + 1) + b];
        atomicAdd(&cnti[b], s);
    }
    __syncthreads();
    if (tid < NB) cntf[tid] = (float)(cnti[tid] < 1 ? 1 : cnti[tid]);
    __syncthreads();

    // protos: thread = channel; loop over (tensor, bin)
    for (int tb = 0; tb < 2 * NB; ++tb) {
        int tns = tb >> 6, b = tb & 63;
        float m = __hip_atomic_load(&sums[(tns * NB + b) * CCH + tid],
                                    __ATOMIC_RELAXED, __HIP_MEMORY_SCOPE_AGENT) / cntf[b];
        float sq = m * m;
        #pragma unroll
        for (int o = 32; o; o >>= 1) sq += __shfl_xor(sq, o, 64);
        if (lane == 0) redw[wv] = sq;
        __syncthreads();
        float nrm = sqrtf(redw[0] + redw[1] + redw[2] + redw[3]);
        float* dp = tns ? pT : pS;
        dp[b * CCH + tid] = m / fmaxf(nrm, 1e-12f);
        __syncthreads();
    }

    // sims + loss: thread handles 16 (i,j) pairs
    float es = 0.0f;
    for (int pr = tid; pr < NB * NB; pr += 256) {
        int i = pr >> 6, j = pr & 63;
        const float4* Si = (const float4*)(pS + i * CCH);
        const float4* Sj = (const float4*)(pS + j * CCH);
        const float4* Ti = (const float4*)(pT + i * CCH);
        const float4* Tj = (const float4*)(pT + j * CCH);
        float dS = 0.0f, dT = 0.0f;
        #pragma unroll 4
        for (int k = 0; k < CCH / 4; ++k) {
            float4 a = Si[k], b = Sj[k];
            dS += a.x * b.x + a.y * b.y + a.z * b.z + a.w * b.w;
            float4 c = Ti[k], d = Tj[k];
            dT += c.x * d.x + c.y * d.y + c.z * d.z + c.w * d.w;
        }
        float e = dS - dT;
        es += e * e;
    }
    #pragma unroll
    for (int o = 32; o; o >>= 1) es += __shfl_xor(es, o, 64);
    if (lane == 0) redw[wv] = es;
    __syncthreads();
    if (tid == 0)
        out[0] = (redw[0] + redw[1] + redw[2] + redw[3]) * (1.0f / (float)(NB * NB));
}

extern "C" void kernel_launch(void* const* d_in, const int* in_sizes, int n_in,
                              void* d_out, int out_size, void* d_ws, size_t ws_size,
                              hipStream_t stream) {
    const float* predsS = (const float*)d_in[0];
    const float* predsT = (const float*)d_in[1];
    const float* depth  = (const float*)d_in[2];
    char* ws = (char*)d_ws;
    float* sums = (float*)(ws + WS_SUMS);
    unsigned short* hist = (unsigned short*)(ws + WS_HIST);
    unsigned char* idx = (unsigned char*)(ws + WS_IDX);
    float* pS = (float*)(ws + WS_PS);
    float* pT = (float*)(ws + WS_PT);
    unsigned int* ticket = (unsigned int*)(ws + WS_TICKET);

    k_idx<<<NIDXBLK, 256, 0, stream>>>(depth, idx, hist, sums, ticket);
    k_msum<<<GRID_MS, 256, 0, stream>>>(predsS, predsT, idx, sums, hist,
                                        pS, pT, ticket, (float*)d_out);
}

// Round 4
// 208.806 us; speedup vs baseline: 2.9619x; 2.9619x over previous
//
#include <hip/hip_runtime.h>

#define NB     64
#define CCH    256
#define HW     20480       // 128*160
#define NBATCH 4

// Workspace layout (bytes):
#define WS_SUMS   0          // [2][64][256] f32 = 131072, zeroed by memsetAsync
#define WS_COUNTS 131072     // [65] i32 = 260
#define WS_ACC    131332     // f32
#define WS_TICKET 131336     // u32
#define WS_ZERO   131340     // memset range [0, WS_ZERO)
#define WS_PS     131584     // [64][256] f32
#define WS_PT     197120     // [64][256] f32  (end 262656)

typedef __attribute__((ext_vector_type(8))) short short8;
typedef __attribute__((ext_vector_type(4))) float f32x4;

#define STRIDE 136   // shorts per LDS row: 128 + 8 pad; 272 B = 17*16 -> every row 16B-aligned

// ---------------------------------------------------------------------------
// Main kernel: segment-sum as one-hot MFMA, fully coalesced through LDS.
// Block: (tensor, n, 64-channel slice cs, 640-pixel range). 1024 blocks.
// Per 128-px tile: stage 64ch x 128px as bf16 hi/lo in LDS, then
// D[bin][ch] += onehot(bin(px)) * x  via 16x16x32 bf16 MFMA (hi then lo).
// Verified layouts (R3 passed): A: m=lane&15,k=q*8+j; B: n=lane&15,k=q*8+j;
// D: col=lane&15, row=q*4+reg.
__global__ __launch_bounds__(256, 4)
void k_msum(const float* __restrict__ predsS,
            const float* __restrict__ predsT,
            const float* __restrict__ depth,
            float* __restrict__ sums,
            int* __restrict__ counts) {
    int tid = threadIdx.x;
    int blk = blockIdx.x;            // 0..1023
    int group = blk >> 5;            // 0..31
    int prange = blk & 31;
    int tensor = group >> 4;
    int n = (group >> 2) & 3;
    int cs = group & 3;
    int hw0 = prange * 640;

    const float* xbase = (tensor ? predsT : predsS) + (size_t)(n * CCH + cs * 64) * HW;
    const float* dbase = depth + n * HW;

    __shared__ short sHi[64][STRIDE];
    __shared__ short sLo[64][STRIDE];
    __shared__ unsigned char sBin[128];
    __shared__ int lhist[NB + 1];

    bool desig = (tensor == 0) && (cs == 0);   // 128 blocks also build histogram
    if (desig) for (int i = tid; i < NB + 1; i += 256) lhist[i] = 0;

    int lane = tid & 63;
    int wv = tid >> 6;
    int l15 = lane & 15;
    int q = lane >> 4;
    int r0 = tid >> 5;               // 0..7: row within 8-row group
    int c0 = (tid & 31) * 4;         // 4-float column offset

    f32x4 acc[4];
    #pragma unroll
    for (int mt = 0; mt < 4; ++mt) acc[mt] = (f32x4)0.0f;

    for (int tt = 0; tt < 5; ++tt) {
        int px0 = hw0 + tt * 128;
        // bins for this tile (512 B coalesced depth read)
        if (tid < 128) {
            float f = dbase[px0 + tid] * 64.0f;
            int b;
            if (!(f >= 0.0f) || f > 64.0f) b = NB;   // NaN via !(f>=0)
            else b = (int)f;
            sBin[tid] = (unsigned char)b;
            if (desig) atomicAdd(&lhist[b], 1);
        }
        // stage 64ch x 128px: load all 8 float4 first (independent, in flight)
        float4 vv[8];
        #pragma unroll
        for (int rr = 0; rr < 8; ++rr)
            vv[rr] = *(const float4*)(xbase + (size_t)(rr * 8 + r0) * HW + px0 + c0);
        #pragma unroll
        for (int rr = 0; rr < 8; ++rr) {
            int r = rr * 8 + r0;
            unsigned u0 = __float_as_uint(vv[rr].x), u1 = __float_as_uint(vv[rr].y);
            unsigned u2 = __float_as_uint(vv[rr].z), u3 = __float_as_uint(vv[rr].w);
            unsigned h0 = u0 & 0xFFFF0000u, h1 = u1 & 0xFFFF0000u;
            unsigned h2 = u2 & 0xFFFF0000u, h3 = u3 & 0xFFFF0000u;
            uint2 hw_;
            hw_.x = (u0 >> 16) | h1;
            hw_.y = (u2 >> 16) | h3;
            unsigned l0 = __float_as_uint(vv[rr].x - __uint_as_float(h0));
            unsigned l1 = __float_as_uint(vv[rr].y - __uint_as_float(h1));
            unsigned l2 = __float_as_uint(vv[rr].z - __uint_as_float(h2));
            unsigned l3 = __float_as_uint(vv[rr].w - __uint_as_float(h3));
            uint2 lw_;
            lw_.x = (l0 >> 16) | (l1 & 0xFFFF0000u);
            lw_.y = (l2 >> 16) | (l3 & 0xFFFF0000u);
            *(uint2*)&sHi[r][c0] = hw_;
            *(uint2*)&sLo[r][c0] = lw_;
        }
        __syncthreads();
        // MFMA phase: wave wv handles channels [wv*16, wv*16+16)
        #pragma unroll
        for (int ks = 0; ks < 4; ++ks) {
            unsigned long long bv = *(const unsigned long long*)&sBin[ks * 32 + q * 8];
            short8 bHi = *(const short8*)&sHi[wv * 16 + l15][ks * 32 + q * 8];
            short8 bLo = *(const short8*)&sLo[wv * 16 + l15][ks * 32 + q * 8];
            #pragma unroll
            for (int mt = 0; mt < 4; ++mt) {
                int tgt = mt * 16 + l15;
                short8 afr;
                #pragma unroll
                for (int j = 0; j < 8; ++j)
                    afr[j] = ((int)((bv >> (8 * j)) & 0xFFull) == tgt) ? (short)0x3F80 : (short)0;
                acc[mt] = __builtin_amdgcn_mfma_f32_16x16x32_bf16(afr, bHi, acc[mt], 0, 0, 0);
                acc[mt] = __builtin_amdgcn_mfma_f32_16x16x32_bf16(afr, bLo, acc[mt], 0, 0, 0);
            }
        }
        __syncthreads();
    }
    // flush: 16 wave-atomics, each 4 consecutive 64B lines
    float* dst = sums + (size_t)tensor * NB * CCH + cs * 64 + wv * 16 + l15;
    #pragma unroll
    for (int mt = 0; mt < 4; ++mt)
        #pragma unroll
        for (int r = 0; r < 4; ++r)
            atomicAdd(&dst[(mt * 16 + q * 4 + r) * CCH], acc[mt][r]);
    if (desig) {
        __syncthreads();
        for (int i = tid; i < NB + 1; i += 256)
            if (lhist[i] != 0) atomicAdd(&counts[i], lhist[i]);
    }
}

// ---------------------------------------------------------------------------
// Protos: 64 blocks (one per bin) x 256 threads (one per channel).
__global__ __launch_bounds__(256) void k_protos(const float* __restrict__ sums,
                                                const int* __restrict__ counts,
                                                float* __restrict__ pS,
                                                float* __restrict__ pT) {
    int b = blockIdx.x, t = threadIdx.x;
    int ci = counts[b];
    float cnt = (float)(ci < 1 ? 1 : ci);
    float mS = sums[b * CCH + t] / cnt;
    float mT = sums[(NB + b) * CCH + t] / cnt;
    float ss = mS * mS, st = mT * mT;
    #pragma unroll
    for (int o = 32; o; o >>= 1) {
        ss += __shfl_xor(ss, o, 64);
        st += __shfl_xor(st, o, 64);
    }
    __shared__ float rs[4], rt[4];
    int w = t >> 6;
    if ((t & 63) == 0) { rs[w] = ss; rt[w] = st; }
    __syncthreads();
    float nS = sqrtf(rs[0] + rs[1] + rs[2] + rs[3]);
    float nT = sqrtf(rt[0] + rt[1] + rt[2] + rt[3]);
    pS[b * CCH + t] = mS / fmaxf(nS, 1e-12f);
    pT[b * CCH + t] = mT / fmaxf(nT, 1e-12f);
}

// ---------------------------------------------------------------------------
// Sims + loss: 64 blocks (row i) x 256 threads (64 cols x 4 segments).
// Last block (ticket) writes the scalar output.
__global__ __launch_bounds__(256) void k_sim(const float* __restrict__ pS,
                                             const float* __restrict__ pT,
                                             float* __restrict__ acc,
                                             unsigned int* __restrict__ ticket,
                                             float* __restrict__ out) {
    int i = blockIdx.x;
    int t = threadIdx.x;
    int j = t & 63, seg = t >> 6;
    __shared__ float rowS[CCH], rowT[CCH];
    rowS[t] = pS[i * CCH + t];
    rowT[t] = pT[i * CCH + t];
    __syncthreads();
    const float4* Sj = (const float4*)(pS + j * CCH + seg * 64);
    const float4* Tj = (const float4*)(pT + j * CCH + seg * 64);
    const float4* Si = (const float4*)(rowS + seg * 64);
    const float4* Ti = (const float4*)(rowT + seg * 64);
    float dS = 0.0f, dT = 0.0f;
    #pragma unroll
    for (int k = 0; k < 16; ++k) {
        float4 a = Si[k], b = Sj[k];
        dS += a.x * b.x + a.y * b.y + a.z * b.z + a.w * b.w;
        float4 c = Ti[k], d = Tj[k];
        dT += c.x * d.x + c.y * d.y + c.z * d.z + c.w * d.w;
    }
    __shared__ float sS[4][64], sT[4][64];
    sS[seg][j] = dS;
    sT[seg][j] = dT;
    __syncthreads();
    if (t < 64) {
        float fS = sS[0][t] + sS[1][t] + sS[2][t] + sS[3][t];
        float fT = sT[0][t] + sT[1][t] + sT[2][t] + sT[3][t];
        float e = fS - fT;
        e = e * e;
        #pragma unroll
        for (int o = 32; o; o >>= 1) e += __shfl_xor(e, o, 64);
        if (t == 0) {
            atomicAdd(acc, e);
            __threadfence();
            unsigned int r = atomicAdd(ticket, 1u);
            if (r == NB - 1) {
                float tot = atomicAdd(acc, 0.0f);   // device-scope atomic read
                out[0] = tot * (1.0f / (float)(NB * NB));
            }
        }
    }
}

extern "C" void kernel_launch(void* const* d_in, const int* in_sizes, int n_in,
                              void* d_out, int out_size, void* d_ws, size_t ws_size,
                              hipStream_t stream) {
    const float* predsS = (const float*)d_in[0];
    const float* predsT = (const float*)d_in[1];
    const float* depth  = (const float*)d_in[2];
    char* ws = (char*)d_ws;
    float* sums = (float*)(ws + WS_SUMS);
    int* counts = (int*)(ws + WS_COUNTS);
    float* acc = (float*)(ws + WS_ACC);
    unsigned int* ticket = (unsigned int*)(ws + WS_TICKET);
    float* pS = (float*)(ws + WS_PS);
    float* pT = (float*)(ws + WS_PT);

    hipMemsetAsync(ws, 0, WS_ZERO, stream);
    k_msum<<<1024, 256, 0, stream>>>(predsS, predsT, depth, sums, counts);
    k_protos<<<NB, 256, 0, stream>>>(sums, counts, pS, pT);
    k_sim<<<NB, 256, 0, stream>>>(pS, pT, acc, ticket, (float*)d_out);
}